// Round 1
// baseline (332.043 us; speedup 1.0000x reference)
//
#include <hip/hip_runtime.h>

// ExpandEvecs: out[b][k][n][m] = sum_{j<=k} e[b][n][j] * e[b][m][j]
// B=4, C=1, N=1024, K=16. fp32 in / fp32 out. Output 268.4 MB => write-BW
// bound; fill-rate ceiling ~6.5 TB/s => ~41 us floor.
//
// R5 change (k-parallel recompute): previous kernel kept the cumsum over k in
// registers (1 FMA/element) but that forced (a) a tiny 512-block grid and
// (b) stores whose source regs are immediately re-accumulated, so the
// compiler serializes each k-step on s_waitcnt vmcnt before reusing acc —
// measured 1.05 TB/s write stream, VALUBusy 5%, Occupancy 10%.
// Now each block owns ONE (b, k, 8-row chunk) and recomputes the k-prefix
// from scratch (<=16 FMA/element, still trivially cheap at 5% VALU):
//   * grid 512 -> 8192 blocks: full occupancy, fill-kernel-like parallelism
//   * accumulate fully in regs, then 8 contiguous float4 stores and EXIT —
//     no register-reuse hazard behind any store, maximal writes in flight.
// k-guards are block-uniform scalar branches (no divergence); low-k blocks
// skip dead operand loads too.

#define BB 4
#define NN 1024
#define KK 16
#define ROWS 8
#define NCHUNK (NN / ROWS)   // 128 n-chunks

__global__ __launch_bounds__(256) void ExpandEvecs_75780402970966_kernel(
    const float* __restrict__ ev,   // [B][N][K] float32
    float* __restrict__ out)        // [B][K][N][N] float32
{
    const int tid = threadIdx.x;
    const int m0  = tid << 2;                 // 256 threads x 4 m = all 1024 m
    const unsigned bid = blockIdx.x;
    const int grp = bid & (NCHUNK - 1);       // n-chunk (low bits: consecutive
    const int bk  = bid >> 7;                 //   blocks write one k-plane)
    const int k   = bk & (KK - 1);            // this block's output level
    const int b   = bk >> 4;
    const int n0  = grp * ROWS;

    const float* eb = ev + (size_t)b * NN * KK;   // this batch's slab (64 KiB)

    float acc[ROWS][4];
#pragma unroll
    for (int r = 0; r < ROWS; ++r)
#pragma unroll
        for (int v = 0; v < 4; ++v) acc[r][v] = 0.0f;

#pragma unroll
    for (int kb = 0; kb < KK / 4; ++kb) {      // j in blocks of 4
        if (kb * 4 <= k) {                     // block-uniform: skip dead blocks
            float4 em4[4];                     // this thread's 4 m-rows
#pragma unroll
            for (int v = 0; v < 4; ++v)
                em4[v] = *(const float4*)(eb + (size_t)(m0 + v) * KK + kb * 4);

            float4 en4[ROWS];                  // block-uniform -> scalar loads
#pragma unroll
            for (int r = 0; r < ROWS; ++r)
                en4[r] = *(const float4*)(eb + (size_t)(n0 + r) * KK + kb * 4);

#pragma unroll
            for (int kk = 0; kk < 4; ++kk) {
                const int j = kb * 4 + kk;
                if (j <= k) {                  // block-uniform guard
#pragma unroll
                    for (int r = 0; r < ROWS; ++r) {
                        const float enk = ((const float*)&en4[r])[kk];
#pragma unroll
                        for (int v = 0; v < 4; ++v)
                            acc[r][v] = fmaf(((const float*)&em4[v])[kk], enk,
                                             acc[r][v]);
                    }
                }
            }
        }
    }

    // Epilogue: 8 contiguous float4 stores (32 KiB/block, full cache lines),
    // then the wave exits — nothing ever waits on these stores.
    const size_t kplane = (size_t)NN * NN;
    float* outk = out + ((size_t)(b * KK + k)) * kplane
                      + (size_t)n0 * NN + (size_t)m0;
#pragma unroll
    for (int r = 0; r < ROWS; ++r)
        *(float4*)(outk + (size_t)r * NN) =
            make_float4(acc[r][0], acc[r][1], acc[r][2], acc[r][3]);
}

extern "C" void kernel_launch(void* const* d_in, const int* in_sizes, int n_in,
                              void* d_out, int out_size, void* d_ws, size_t ws_size,
                              hipStream_t stream) {
    const float* ev = (const float*)d_in[0];
    float* out = (float*)d_out;

    const int grid = BB * KK * NCHUNK;   // 8192 blocks, 256 threads
    ExpandEvecs_75780402970966_kernel<<<grid, 256, 0, stream>>>(ev, out);
}

// Round 2
// 264.529 us; speedup vs baseline: 1.2552x; 1.2552x over previous
//
#include <hip/hip_runtime.h>

// ExpandEvecs: out[b][k][n][m] = sum_{j<=k} e[b][n][j] * e[b][m][j]
// B=4, C=1, N=1024, K=16. fp32 in / fp32 out. Output 268.4 MB => write-BW
// bound; fill-rate ceiling ~6.5 TB/s => ~41 us floor.
//
// R6 (transpose + unfenced stream). Post-mortem of R4/R5:
//   R4 (256 us): cumsum in regs, stores' source regs re-accumulated next
//     k-step -> compiler drains vmcnt each step -> ~1 TB/s cap.
//   R5 (332 us): unfenced store burst BUT 10x more divergent gathers
//     (e[m][k] reads are 64-lanes-x-256B-stride = 64 lines/instr); became
//     address-unit bound, NOT store bound.
// Fix both:
//   1. tiny pre-kernel transposes evecs into d_ws: evT[b][k][m] (256 KB).
//      Fixed-k reads across m are now perfectly coalesced (1 KB/instr).
//   2. main kernel: per thread 16 coalesced loads -> in-place prefix
//      v[k] = v[k]*en[k] + v[k-1] (16 distinct result quads, en[k] is
//      block-uniform scalar) -> 16 unfenced float4 stores -> exit.
//      No register ever re-used behind a store; no divergent gather.

#define BB 4
#define NN 1024
#define KK 16

__global__ __launch_bounds__(256) void ExpandEvecs_75780402970966_evT(
    const float* __restrict__ ev,   // [B][N][K]
    float* __restrict__ evT)        // [B][K][N]
{
    const int b  = blockIdx.x >> 2;
    const int mc = blockIdx.x & 3;
    const int m  = mc * 256 + threadIdx.x;
    const float* src = ev + (size_t)(b * NN + m) * KK;
    float* dst = evT + (size_t)b * KK * NN + m;
#pragma unroll
    for (int k = 0; k < KK; ++k)
        dst[(size_t)k * NN] = src[k];   // coalesced stores, tiny gather reads
}

template <bool TRANS>
__global__ __launch_bounds__(256) void ExpandEvecs_75780402970966_kernel(
    const float* __restrict__ ev,   // [B][N][K] float32
    const float* __restrict__ evT,  // [B][K][N] float32 (workspace)
    float* __restrict__ out)        // [B][K][N][N] float32
{
    const int tid = threadIdx.x;
    const int m0  = tid << 2;                 // 256 threads x 4 m = all 1024 m
    const int n   = blockIdx.x & (NN - 1);    // consecutive blocks: same b,
    const int b   = blockIdx.x >> 10;         //   adjacent n rows

    // Block-uniform n-row -> scalar loads.
    const float* __restrict__ en = ev + (size_t)(b * NN + n) * KK;

    float4 v[KK];
    if (TRANS) {
        // Coalesced: per k, 64 lanes x 16 B = 1 KB contiguous. L2-resident.
        const float* __restrict__ eT = evT + (size_t)b * KK * NN + m0;
#pragma unroll
        for (int k = 0; k < KK; ++k)
            v[k] = *(const float4*)(eT + (size_t)k * NN);
    } else {
        // Fallback (no workspace): thread's 4 m-rows are one contiguous
        // 256 B run; load 16 float4 then component-select in registers.
        float4 f[16];
        const float* base = ev + ((size_t)b * NN + m0) * KK;
#pragma unroll
        for (int i = 0; i < 16; ++i)
            f[i] = *(const float4*)(base + i * 4);
#pragma unroll
        for (int k = 0; k < KK; ++k) {
            float4 t;
            t.x = ((const float*)&f[0  + (k >> 2)])[k & 3];
            t.y = ((const float*)&f[4  + (k >> 2)])[k & 3];
            t.z = ((const float*)&f[8  + (k >> 2)])[k & 3];
            t.w = ((const float*)&f[12 + (k >> 2)])[k & 3];
            v[k] = t;
        }
    }

    // In-place inclusive prefix over k (same summation order as reference
    // cumsum): v[k] <- v[k]*en[k] + v[k-1]. Results land in 16 distinct
    // register quads -> the store burst below has no source-reg reuse.
    {
        const float e0 = en[0];
        v[0].x *= e0; v[0].y *= e0; v[0].z *= e0; v[0].w *= e0;
    }
#pragma unroll
    for (int k = 1; k < KK; ++k) {
        const float ek = en[k];
        v[k].x = fmaf(v[k].x, ek, v[k - 1].x);
        v[k].y = fmaf(v[k].y, ek, v[k - 1].y);
        v[k].z = fmaf(v[k].z, ek, v[k - 1].z);
        v[k].w = fmaf(v[k].w, ek, v[k - 1].w);
    }

    // 16 unfenced float4 stores (16 KB in flight per wave), then exit.
    const size_t kplane = (size_t)NN * NN;
    float* ob = out + (size_t)b * KK * kplane + (size_t)n * NN + m0;
#pragma unroll
    for (int k = 0; k < KK; ++k)
        *(float4*)(ob + (size_t)k * kplane) = v[k];
}

extern "C" void kernel_launch(void* const* d_in, const int* in_sizes, int n_in,
                              void* d_out, int out_size, void* d_ws, size_t ws_size,
                              hipStream_t stream) {
    const float* ev = (const float*)d_in[0];
    float* out = (float*)d_out;

    const size_t evT_bytes = (size_t)BB * KK * NN * sizeof(float);  // 256 KB
    if (ws_size >= evT_bytes && d_ws != nullptr) {
        float* evT = (float*)d_ws;
        ExpandEvecs_75780402970966_evT<<<BB * 4, 256, 0, stream>>>(ev, evT);
        ExpandEvecs_75780402970966_kernel<true>
            <<<BB * NN, 256, 0, stream>>>(ev, evT, out);
    } else {
        ExpandEvecs_75780402970966_kernel<false>
            <<<BB * NN, 256, 0, stream>>>(ev, nullptr, out);
    }
}

// Round 3
// 257.791 us; speedup vs baseline: 1.2880x; 1.0261x over previous
//
#include <hip/hip_runtime.h>

// ExpandEvecs: out[b][k][n][m] = sum_{j<=k} e[b][n][j] * e[b][m][j]
// B=4, C=1, N=1024, K=16. fp32 in / fp32 out. Output 268.4 MB => write-BW
// bound; fill-rate ceiling ~6.5 TB/s => ~41 us kernel floor. Measured
// dur_us includes the harness's 1.07 GB re-poison fill (~162 us): every
// rocprof top-5 row is fillBufferAligned at ~160-165 us, so the kernel
// itself is < 160 us in all rounds.
//
// History:
//   R4 (dur 256): k-cumsum in regs, 512 blocks, per-k-step store+reuse.
//   R5 (dur 332): fill-like linear stores (32 KB/block) BUT divergent
//     256B-stride gathers of e[m][k] -> address-unit bound.
//   R6 (dur 264): transposed loads (coalesced, L2-resident), unfenced
//     stores, 4096 blocks -- but each wave scatters 16 stores across
//     16 k-planes 4 MB apart: 64 interleaved write streams, ~2.7 TB/s.
// R7 = R5's store structure + R6's load structure:
//   * pre-kernel transposes evecs into d_ws: evT[b][k][m] (256 KB).
//   * one block per (b,k,8-row chunk): <=16 coalesced evT float4 loads,
//     block-uniform s_loads for n-rows, acc in regs, then a single
//     32 KB contiguous unfenced store burst and exit. Consecutive blocks
//     write consecutive 32 KB -> global write order is a linear sweep,
//     same shape as the 6.5 TB/s fill kernel.

#define BB 4
#define NN 1024
#define KK 16
#define ROWS 8
#define NCHUNK (NN / ROWS)   // 128 n-chunks per (b,k) plane

__global__ __launch_bounds__(256) void ExpandEvecs_75780402970966_evT(
    const float* __restrict__ ev,   // [B][N][K]
    float* __restrict__ evT)        // [B][K][N]
{
    const int b  = blockIdx.x >> 2;
    const int mc = blockIdx.x & 3;
    const int m  = mc * 256 + threadIdx.x;
    const float* src = ev + (size_t)(b * NN + m) * KK;
    float* dst = evT + (size_t)b * KK * NN + m;
#pragma unroll
    for (int k = 0; k < KK; ++k)
        dst[(size_t)k * NN] = src[k];   // coalesced stores, tiny gather reads
}

__global__ __launch_bounds__(256) void ExpandEvecs_75780402970966_kernel(
    const float* __restrict__ ev,   // [B][N][K] float32 (for uniform n-rows)
    const float* __restrict__ evT,  // [B][K][N] float32 (workspace)
    float* __restrict__ out)        // [B][K][N][N] float32
{
    const int tid = threadIdx.x;
    const int m0  = tid << 2;                 // 256 threads x 4 m = all 1024 m
    const unsigned bid = blockIdx.x;
    const int grp = bid & (NCHUNK - 1);       // fastest: linear sweep within
    const int bk  = bid >> 7;                 //   a (b,k) plane
    const int k   = bk & (KK - 1);
    const int b   = bk >> 4;
    const int n0  = grp * ROWS;

    const float* __restrict__ eb = ev + (size_t)b * NN * KK;
    const float* __restrict__ eT = evT + (size_t)b * KK * NN + m0;

    float acc[ROWS][4];
#pragma unroll
    for (int r = 0; r < ROWS; ++r)
#pragma unroll
        for (int v = 0; v < 4; ++v) acc[r][v] = 0.0f;

#pragma unroll
    for (int kb = 0; kb < KK / 4; ++kb) {      // j in blocks of 4
        if (kb * 4 <= k) {                     // block-uniform: skip dead work
            float4 em4[4];                     // em4[jj] = evT[j][m0..m0+3]
#pragma unroll
            for (int jj = 0; jj < 4; ++jj)
                em4[jj] = *(const float4*)(eT + (size_t)(kb * 4 + jj) * NN);

            float4 en4[ROWS];                  // block-uniform -> s_load_x4
#pragma unroll
            for (int r = 0; r < ROWS; ++r)
                en4[r] = *(const float4*)(eb + (size_t)(n0 + r) * KK + kb * 4);

#pragma unroll
            for (int jj = 0; jj < 4; ++jj) {
                const int j = kb * 4 + jj;
                if (j <= k) {                  // block-uniform guard
#pragma unroll
                    for (int r = 0; r < ROWS; ++r) {
                        const float enk = ((const float*)&en4[r])[jj];
#pragma unroll
                        for (int v = 0; v < 4; ++v)
                            acc[r][v] = fmaf(((const float*)&em4[jj])[v], enk,
                                             acc[r][v]);
                    }
                }
            }
        }
    }

    // Epilogue: 8 contiguous float4 stores = 32 KiB/block, consecutive
    // blocks -> consecutive 32 KiB. Nothing ever waits on these stores.
    const size_t kplane = (size_t)NN * NN;
    float* ob = out + ((size_t)(b * KK + k)) * kplane
                    + (size_t)n0 * NN + (size_t)m0;
#pragma unroll
    for (int r = 0; r < ROWS; ++r)
        *(float4*)(ob + (size_t)r * NN) =
            make_float4(acc[r][0], acc[r][1], acc[r][2], acc[r][3]);
}

// Fallback (no workspace): R6's single kernel, one block per (b,n) row,
// reads ev directly with in-register component select. Correctness only.
__global__ __launch_bounds__(256) void ExpandEvecs_75780402970966_fallback(
    const float* __restrict__ ev, float* __restrict__ out)
{
    const int tid = threadIdx.x;
    const int m0  = tid << 2;
    const int n   = blockIdx.x & (NN - 1);
    const int b   = blockIdx.x >> 10;
    const float* __restrict__ en = ev + (size_t)(b * NN + n) * KK;

    float4 f[16];
    const float* base = ev + ((size_t)b * NN + m0) * KK;
#pragma unroll
    for (int i = 0; i < 16; ++i)
        f[i] = *(const float4*)(base + i * 4);

    float4 v[KK];
#pragma unroll
    for (int k = 0; k < KK; ++k) {
        float4 t;
        t.x = ((const float*)&f[0  + (k >> 2)])[k & 3];
        t.y = ((const float*)&f[4  + (k >> 2)])[k & 3];
        t.z = ((const float*)&f[8  + (k >> 2)])[k & 3];
        t.w = ((const float*)&f[12 + (k >> 2)])[k & 3];
        v[k] = t;
    }
    {
        const float e0 = en[0];
        v[0].x *= e0; v[0].y *= e0; v[0].z *= e0; v[0].w *= e0;
    }
#pragma unroll
    for (int k = 1; k < KK; ++k) {
        const float ek = en[k];
        v[k].x = fmaf(v[k].x, ek, v[k - 1].x);
        v[k].y = fmaf(v[k].y, ek, v[k - 1].y);
        v[k].z = fmaf(v[k].z, ek, v[k - 1].z);
        v[k].w = fmaf(v[k].w, ek, v[k - 1].w);
    }
    const size_t kplane = (size_t)NN * NN;
    float* ob = out + (size_t)b * KK * kplane + (size_t)n * NN + m0;
#pragma unroll
    for (int k = 0; k < KK; ++k)
        *(float4*)(ob + (size_t)k * kplane) = v[k];
}

extern "C" void kernel_launch(void* const* d_in, const int* in_sizes, int n_in,
                              void* d_out, int out_size, void* d_ws, size_t ws_size,
                              hipStream_t stream) {
    const float* ev = (const float*)d_in[0];
    float* out = (float*)d_out;

    const size_t evT_bytes = (size_t)BB * KK * NN * sizeof(float);  // 256 KB
    if (ws_size >= evT_bytes && d_ws != nullptr) {
        float* evT = (float*)d_ws;
        ExpandEvecs_75780402970966_evT<<<BB * 4, 256, 0, stream>>>(ev, evT);
        ExpandEvecs_75780402970966_kernel
            <<<BB * KK * NCHUNK, 256, 0, stream>>>(ev, evT, out);
    } else {
        ExpandEvecs_75780402970966_fallback
            <<<BB * NN, 256, 0, stream>>>(ev, out);
    }
}